// Round 2
// 188.091 us; speedup vs baseline: 1.0771x; 1.0771x over previous
//
#include <hip/hip_runtime.h>

#define DIM  33
#define DIM2 1089      // 33*33
#define DIM3 35937     // 33*33*33
#define HW   2073600   // 1080*1920
#define HW4  518400    // HW/4
#define NPIX 8294400   // 4*HW
#define GROUPS (NPIX / 4)                     // 2,073,600 float4 pixel-groups
#define LDS_BYTES (DIM3 * 4)                  // 143,748 B — needs the 160KB attr
#define MAIN_BLOCKS  256
#define MAIN_THREADS 1024
#define NB_MAX ((3 * DIM3 + 255) / 256)       // 422 maxabs blocks -> 422 slots

// Native vector type — HIP's float4 is a class, rejected by nontemporal builtins.
typedef float vf4 __attribute__((ext_vector_type(4)));

// ws layout (main path): float slots[NB_MAX] at byte 64 (every slot written
// each call -> no memset needed, poison-safe).
// ws layout (fallback):  2.3MB fp16 table at byte 64.
#define TBL_OFF 64

__device__ __forceinline__ float ub(unsigned v, int b) {
    return (float)((v >> (8 * b)) & 0xffu);   // -> v_cvt_f32_ubyteN
}

// ---------------------------------------------------------------------------
// Kernel 1: per-block max|LUT| -> plain store to slots[blockIdx].
// No atomics, no zero-init required (all NB_MAX slots are overwritten).
// Side effect: warms all 8 XCD L2s with the LUT for the main kernel's staging.
// ---------------------------------------------------------------------------
__global__ __launch_bounds__(256) void lut_maxabs_blocks(
        const float* __restrict__ lut, float* __restrict__ slots) {
    __shared__ float red[4];
    int i = blockIdx.x * 256 + threadIdx.x;
    float m = 0.0f;
    if (i < 3 * DIM3) m = fabsf(lut[i]);
#pragma unroll
    for (int off = 32; off > 0; off >>= 1)
        m = fmaxf(m, __shfl_down(m, off, 64));
    if ((threadIdx.x & 63) == 0) red[threadIdx.x >> 6] = m;
    __syncthreads();
    if (threadIdx.x == 0)
        slots[blockIdx.x] = fmaxf(fmaxf(red[0], red[1]), fmaxf(red[2], red[3]));
}

// ---------------------------------------------------------------------------
// Kernel 2 (main): fused prep + apply.
//   prologue: reduce 422 slot maxes in-block, quantize float LUT directly
//             into LDS (u8 rgb packed in u32, global scale max/127, +128 bias).
//   body:     grid-stride over float4 pixel groups (static partition — max
//             block work is 8 iterations, identical to the old dynamic-chunk
//             worst case, so no counter / memset / atomics needed).
// ---------------------------------------------------------------------------
extern __shared__ unsigned s_tbl[];

__global__ __launch_bounds__(MAIN_THREADS, 1) void lut_apply_lds(
        const float* __restrict__ x, const float* __restrict__ lut,
        const float* __restrict__ slots, float* __restrict__ out) {
    __shared__ float red[16];

    // --- global max|LUT| from slots (exact same value as the old atomicMax) ---
    float m = 0.0f;
    if (threadIdx.x < NB_MAX) m = slots[threadIdx.x];
#pragma unroll
    for (int off = 32; off > 0; off >>= 1)
        m = fmaxf(m, __shfl_down(m, off, 64));
    if ((threadIdx.x & 63) == 0) red[threadIdx.x >> 6] = m;
    __syncthreads();
    float mx = red[0];
#pragma unroll
    for (int j = 1; j < 16; ++j) mx = fmaxf(mx, red[j]);
    mx = fmaxf(mx, 1e-20f);

    // --- quantize LUT straight into LDS (reads are L2-warm from kernel 1) ---
    const float inv = 127.0f / mx;
    for (int i = threadIdx.x; i < DIM3; i += MAIN_THREADS) {
        int q0 = min(max(__float2int_rn(lut[i]            * inv) + 128, 0), 255);
        int q1 = min(max(__float2int_rn(lut[i + DIM3]     * inv) + 128, 0), 255);
        int q2 = min(max(__float2int_rn(lut[i + 2 * DIM3] * inv) + 128, 0), 255);
        s_tbl[i] = (unsigned)q0 | ((unsigned)q1 << 8) | ((unsigned)q2 << 16);
    }
    __syncthreads();

    const float s_   = mx * (1.0f / 127.0f);
    const float bias = -128.0f * s_;

    for (int g = blockIdx.x * MAIN_THREADS + threadIdx.x; g < GROUPS;
         g += MAIN_BLOCKS * MAIN_THREADS) {
        int n   = g / HW4;
        int rem = g - n * HW4;
        size_t base = (size_t)n * (size_t)(3 * HW) + (size_t)rem * 4;

        const vf4 rv = __builtin_nontemporal_load((const vf4*)(x + base));
        const vf4 gv = __builtin_nontemporal_load((const vf4*)(x + base + HW));
        const vf4 bv = __builtin_nontemporal_load((const vf4*)(x + base + 2 * (size_t)HW));

        float oa[4], ob[4], oc[4];
#pragma unroll
        for (int k = 0; k < 4; ++k) {
            float rs = fminf(fmaxf(rv[k], 0.0f), 1.0f) * 32.0f;
            float gs = fminf(fmaxf(gv[k], 0.0f), 1.0f) * 32.0f;
            float bs = fminf(fmaxf(bv[k], 0.0f), 1.0f) * 32.0f;
            int ri = min((int)rs, 31);   // rs >= 0 so (int) == floor
            int gi = min((int)gs, 31);
            int bi = min((int)bs, 31);
            float fr = rs - (float)ri;
            float fg = gs - (float)gi;
            float fb = bs - (float)bi;

            int i00 = bi * DIM2 + gi * DIM + ri;
            // cXYZ: X=db (b), Y=dg (g), Z=dr (r)
            unsigned c000 = s_tbl[i00];
            unsigned c001 = s_tbl[i00 + 1];
            unsigned c010 = s_tbl[i00 + DIM];
            unsigned c011 = s_tbl[i00 + DIM + 1];
            unsigned c100 = s_tbl[i00 + DIM2];
            unsigned c101 = s_tbl[i00 + DIM2 + 1];
            unsigned c110 = s_tbl[i00 + DIM2 + DIM];
            unsigned c111 = s_tbl[i00 + DIM2 + DIM + 1];

            float wr1 = fr, wr0 = 1.0f - fr;
            float wg1 = fg, wg0 = 1.0f - fg;
            float wb1 = fb, wb0 = 1.0f - fb;
            float wb0g0 = wb0 * wg0, wb0g1 = wb0 * wg1;
            float wb1g0 = wb1 * wg0, wb1g1 = wb1 * wg1;
            float w000 = wb0g0 * wr0, w001 = wb0g0 * wr1;
            float w010 = wb0g1 * wr0, w011 = wb0g1 * wr1;
            float w100 = wb1g0 * wr0, w101 = wb1g0 * wr1;
            float w110 = wb1g1 * wr0, w111 = wb1g1 * wr1;

            float a0, a1, a2;
            a0 =      w000 * ub(c000, 0);
            a1 =      w000 * ub(c000, 1);
            a2 =      w000 * ub(c000, 2);
            a0 = fmaf(w001,  ub(c001, 0), a0);
            a1 = fmaf(w001,  ub(c001, 1), a1);
            a2 = fmaf(w001,  ub(c001, 2), a2);
            a0 = fmaf(w010,  ub(c010, 0), a0);
            a1 = fmaf(w010,  ub(c010, 1), a1);
            a2 = fmaf(w010,  ub(c010, 2), a2);
            a0 = fmaf(w011,  ub(c011, 0), a0);
            a1 = fmaf(w011,  ub(c011, 1), a1);
            a2 = fmaf(w011,  ub(c011, 2), a2);
            a0 = fmaf(w100,  ub(c100, 0), a0);
            a1 = fmaf(w100,  ub(c100, 1), a1);
            a2 = fmaf(w100,  ub(c100, 2), a2);
            a0 = fmaf(w101,  ub(c101, 0), a0);
            a1 = fmaf(w101,  ub(c101, 1), a1);
            a2 = fmaf(w101,  ub(c101, 2), a2);
            a0 = fmaf(w110,  ub(c110, 0), a0);
            a1 = fmaf(w110,  ub(c110, 1), a1);
            a2 = fmaf(w110,  ub(c110, 2), a2);
            a0 = fmaf(w111,  ub(c111, 0), a0);
            a1 = fmaf(w111,  ub(c111, 1), a1);
            a2 = fmaf(w111,  ub(c111, 2), a2);

            oa[k] = fmaf(s_, a0, bias);
            ob[k] = fmaf(s_, a1, bias);
            oc[k] = fmaf(s_, a2, bias);
        }
        vf4 s0 = {oa[0], oa[1], oa[2], oa[3]};
        vf4 s1 = {ob[0], ob[1], ob[2], ob[3]};
        vf4 s2 = {oc[0], oc[1], oc[2], oc[3]};
        __builtin_nontemporal_store(s0, (vf4*)(out + base));
        __builtin_nontemporal_store(s1, (vf4*)(out + base + HW));
        __builtin_nontemporal_store(s2, (vf4*)(out + base + 2 * (size_t)HW));
    }
}

// ---------------------------------------------------------------------------
// Fallback path (if the 160KB dynamic-LDS attribute is rejected): round-3's
// verified fp16 64B-entry global-gather kernel (92.9 us main).
// ---------------------------------------------------------------------------
union F4H { vf4 f4; _Float16 h[8]; };

__global__ __launch_bounds__(256) void pack_lut8_kernel(
        const float* __restrict__ lut, vf4* __restrict__ lut8) {
    int i = blockIdx.x * blockDim.x + threadIdx.x;
    if (i >= DIM3) return;
    int b   = i / DIM2;
    int rem = i - b * DIM2;
    int g   = rem / DIM;
    int r   = rem - g * DIM;
    int b1 = min(b + 1, DIM - 1);
    int g1 = min(g + 1, DIM - 1);
    int r1 = min(r + 1, DIM - 1);
    _Float16 h[32];
#pragma unroll
    for (int db = 0; db < 2; ++db)
#pragma unroll
        for (int dg = 0; dg < 2; ++dg)
#pragma unroll
            for (int dr = 0; dr < 2; ++dr) {
                int bb = db ? b1 : b;
                int gg = dg ? g1 : g;
                int rr = dr ? r1 : r;
                int base = bb * DIM2 + gg * DIM + rr;
                int ci = ((db * 2 + dg) * 2 + dr) * 3;
                h[ci + 0] = (_Float16)lut[base];
                h[ci + 1] = (_Float16)lut[base + DIM3];
                h[ci + 2] = (_Float16)lut[base + 2 * DIM3];
            }
#pragma unroll
    for (int k = 24; k < 32; ++k) h[k] = (_Float16)0.0f;
    const vf4* hv = (const vf4*)h;
    vf4* dst = lut8 + (size_t)i * 4;
    dst[0] = hv[0]; dst[1] = hv[1]; dst[2] = hv[2]; dst[3] = hv[3];
}

__global__ __launch_bounds__(256) void lut_apply_fp16x8(
        const float* __restrict__ x, const vf4* __restrict__ lut8,
        float* __restrict__ out) {
    int i4 = blockIdx.x * blockDim.x + threadIdx.x;
    if (i4 >= NPIX / 4) return;
    int n   = i4 / HW4;
    int rem = i4 - n * HW4;
    size_t base = (size_t)n * (size_t)(3 * HW) + (size_t)rem * 4;
    const vf4 rv = __builtin_nontemporal_load((const vf4*)(x + base));
    const vf4 gv = __builtin_nontemporal_load((const vf4*)(x + base + HW));
    const vf4 bv = __builtin_nontemporal_load((const vf4*)(x + base + 2 * (size_t)HW));
    float oa[4], ob[4], oc[4];
#pragma unroll
    for (int k = 0; k < 4; ++k) {
        float rs = fminf(fmaxf(rv[k], 0.0f), 1.0f) * 32.0f;
        float gs = fminf(fmaxf(gv[k], 0.0f), 1.0f) * 32.0f;
        float bs = fminf(fmaxf(bv[k], 0.0f), 1.0f) * 32.0f;
        int ri = min((int)rs, 31);
        int gi = min((int)gs, 31);
        int bi = min((int)bs, 31);
        float fr = rs - (float)ri;
        float fg = gs - (float)gi;
        float fb = bs - (float)bi;
        const vf4* e = lut8 + (size_t)(bi * DIM2 + gi * DIM + ri) * 4;
        F4H q0, q1, q2;
        q0.f4 = e[0]; q1.f4 = e[1]; q2.f4 = e[2];
        float c[24];
#pragma unroll
        for (int j = 0; j < 8; ++j) {
            c[j] = (float)q0.h[j]; c[8 + j] = (float)q1.h[j]; c[16 + j] = (float)q2.h[j];
        }
        float wr[2] = {1.0f - fr, fr};
        float wg[2] = {1.0f - fg, fg};
        float wb[2] = {1.0f - fb, fb};
        float a0 = 0.0f, a1 = 0.0f, a2 = 0.0f;
#pragma unroll
        for (int db = 0; db < 2; ++db)
#pragma unroll
            for (int dg = 0; dg < 2; ++dg) {
                float wbg = wb[db] * wg[dg];
#pragma unroll
                for (int dr = 0; dr < 2; ++dr) {
                    float w = wbg * wr[dr];
                    int ci = ((db * 2 + dg) * 2 + dr) * 3;
                    a0 = fmaf(w, c[ci + 0], a0);
                    a1 = fmaf(w, c[ci + 1], a1);
                    a2 = fmaf(w, c[ci + 2], a2);
                }
            }
        oa[k] = a0; ob[k] = a1; oc[k] = a2;
    }
    vf4 s0 = {oa[0], oa[1], oa[2], oa[3]};
    vf4 s1 = {ob[0], ob[1], ob[2], ob[3]};
    vf4 s2 = {oc[0], oc[1], oc[2], oc[3]};
    __builtin_nontemporal_store(s0, (vf4*)(out + base));
    __builtin_nontemporal_store(s1, (vf4*)(out + base + HW));
    __builtin_nontemporal_store(s2, (vf4*)(out + base + 2 * (size_t)HW));
}

extern "C" void kernel_launch(void* const* d_in, const int* in_sizes, int n_in,
                              void* d_out, int out_size, void* d_ws, size_t ws_size,
                              hipStream_t stream) {
    const float* x   = (const float*)d_in[0];
    const float* lut = (const float*)d_in[1];
    float* out = (float*)d_out;

    float* slots = (float*)((char*)d_ws + TBL_OFF);   // 422 floats, all rewritten

    // Raise the dynamic-LDS cap to 160KB for the main kernel (host-side,
    // capture-safe). Idempotent; done every call so behavior is uniform.
    static hipError_t attr_err = hipFuncSetAttribute(
        (const void*)lut_apply_lds,
        hipFuncAttributeMaxDynamicSharedMemorySize, LDS_BYTES);
    hipError_t err2 = hipFuncSetAttribute(
        (const void*)lut_apply_lds,
        hipFuncAttributeMaxDynamicSharedMemorySize, LDS_BYTES);

    if (attr_err == hipSuccess && err2 == hipSuccess) {
        // 2-dispatch graph: no memset, no atomics, no global tbl round-trip.
        lut_maxabs_blocks<<<NB_MAX, 256, 0, stream>>>(lut, slots);
        lut_apply_lds<<<MAIN_BLOCKS, MAIN_THREADS, LDS_BYTES, stream>>>(
            x, lut, slots, out);
    } else {
        vf4* lut8 = (vf4*)((char*)d_ws + TBL_OFF);    // 2.3MB fp16 table
        pack_lut8_kernel<<<(DIM3 + 255) / 256, 256, 0, stream>>>(lut, lut8);
        lut_apply_fp16x8<<<(GROUPS + 255) / 256, 256, 0, stream>>>(x, lut8, out);
    }
}